// Round 1
// baseline (179.608 us; speedup 1.0000x reference)
//
#include <hip/hip_runtime.h>

#define N 8192
#define T 512
#define S 4
#define ND 8
#define NC 16

__device__ __forceinline__ float dot4(float4 a, float4 b) {
    return a.x*b.x + a.y*b.y + a.z*b.z + a.w*b.w;
}

// b[n*T + t] = proj(n,t) + alpha_Y * Y[n,t-1]   (t >= 1)
// b[n*T + 0] = mu_init + proj(n,0)              (= mu0[n])
__global__ __launch_bounds__(256) void k_bias(
        const float* __restrict__ drivers,
        const float* __restrict__ cov,
        const float* __restrict__ Y,
        const float* __restrict__ gamma_w,
        const float* __restrict__ alpha_w,
        const float* __restrict__ alpha_Y_lag,
        const float* __restrict__ mu_init,
        float* __restrict__ bws) {
    int id = blockIdx.x * blockDim.x + threadIdx.x;   // id = n*T + t
    // weights: uniform scalar loads (L2-broadcast / s_load)
    const float4* g4 = (const float4*)gamma_w;
    const float4* a4 = (const float4*)alpha_w;
    float4 g0 = g4[0], g1 = g4[1];
    float4 w0 = a4[0], w1 = a4[1], w2 = a4[2], w3 = a4[3];

    const float4* d4 = (const float4*)drivers + (size_t)id * 2;
    float4 dA = d4[0], dB = d4[1];
    const float4* c4 = (const float4*)cov + (size_t)id * 4;
    float4 cA = c4[0], cB = c4[1], cC = c4[2], cD = c4[3];

    float proj = dot4(dA, g0) + dot4(dB, g1)
               + dot4(cA, w0) + dot4(cB, w1) + dot4(cC, w2) + dot4(cD, w3);

    int t = id & (T - 1);
    float out;
    if (t == 0) {
        out = mu_init[0] + proj;
    } else {
        out = proj + alpha_Y_lag[0] * Y[id - 1];
    }
    bws[id] = out;
}

// One thread per (s,n) chain. Serial scan over T with float4 I/O.
__global__ __launch_bounds__(64) void k_scan(
        const float* __restrict__ bws,
        const float* __restrict__ eps,
        const float* __restrict__ tilde_psi,
        const float* __restrict__ log_tilde_sigma,
        const float* __restrict__ log_sigma_init,
        float* __restrict__ Zout,
        float* __restrict__ muout) {
    int idx = blockIdx.x * blockDim.x + threadIdx.x;  // idx = s*N + n
    int n = idx & (N - 1);

    float psi    = tilde_psi[0];
    float sigma  = expf(log_tilde_sigma[0]);
    float sigma0 = expf(log_sigma_init[0]);

    const float4* e4 = (const float4*)eps  + (size_t)idx * (T / 4);
    const float4* b4 = (const float4*)bws  + (size_t)n   * (T / 4);
    float4*       z4 = (float4*)Zout       + (size_t)idx * (T / 4);
    float4*       m4 = (float4*)muout      + (size_t)idx * (T / 4);

    // first group: t = 0..3 (t==0 uses mu0 = b.x and sigma0)
    float4 e = e4[0], b = b4[0];
    float4 zo, mo;
    float mu = b.x;                 // mu0
    float Z  = mu + sigma0 * e.x;
    zo.x = Z; mo.x = mu;
    mu = psi * Z + b.y; Z = mu + sigma * e.y; zo.y = Z; mo.y = mu;
    mu = psi * Z + b.z; Z = mu + sigma * e.z; zo.z = Z; mo.z = mu;
    mu = psi * Z + b.w; Z = mu + sigma * e.w; zo.w = Z; mo.w = mu;
    z4[0] = zo; m4[0] = mo;

    #pragma unroll 8
    for (int v = 1; v < T / 4; ++v) {
        e = e4[v]; b = b4[v];
        mu = psi * Z + b.x; Z = mu + sigma * e.x; zo.x = Z; mo.x = mu;
        mu = psi * Z + b.y; Z = mu + sigma * e.y; zo.y = Z; mo.y = mu;
        mu = psi * Z + b.z; Z = mu + sigma * e.z; zo.z = Z; mo.z = mu;
        mu = psi * Z + b.w; Z = mu + sigma * e.w; zo.w = Z; mo.w = mu;
        z4[v] = zo; m4[v] = mo;
    }
}

// lv[s,n,0] = 2*log_sigma_init ; lv[s,n,t>=1] = 2*log_tilde_sigma
__global__ __launch_bounds__(256) void k_lv(
        float* __restrict__ lv,
        const float* __restrict__ lts,
        const float* __restrict__ lsi) {
    int i = blockIdx.x * blockDim.x + threadIdx.x;    // float4 index
    float v = 2.0f * lts[0];
    float4 o = make_float4(v, v, v, v);
    if ((i & (T / 4 - 1)) == 0) o.x = 2.0f * lsi[0];
    ((float4*)lv)[i] = o;
}

extern "C" void kernel_launch(void* const* d_in, const int* in_sizes, int n_in,
                              void* d_out, int out_size, void* d_ws, size_t ws_size,
                              hipStream_t stream) {
    const float* drivers   = (const float*)d_in[0];
    const float* cov       = (const float*)d_in[1];
    const float* Y         = (const float*)d_in[2];
    const float* eps       = (const float*)d_in[3];
    const float* tilde_psi = (const float*)d_in[4];
    const float* gamma_w   = (const float*)d_in[5];
    const float* alpha_w   = (const float*)d_in[6];
    const float* aY        = (const float*)d_in[7];
    const float* lts       = (const float*)d_in[8];
    const float* mu_init   = (const float*)d_in[9];
    const float* lsi       = (const float*)d_in[10];

    float* out   = (float*)d_out;
    const size_t SNT = (size_t)S * N * T;
    float* Zout  = out;
    float* muout = out + SNT;
    float* lvout = out + 2 * SNT;
    // use the lv output region as scratch for b (16 MiB needed, 64 MiB there);
    // k_lv overwrites it AFTER k_scan has consumed it (stream-ordered).
    float* bws   = lvout;

    k_bias<<<(N * T) / 256, 256, 0, stream>>>(drivers, cov, Y, gamma_w, alpha_w,
                                              aY, mu_init, bws);
    k_scan<<<(S * N) / 64, 64, 0, stream>>>(bws, eps, tilde_psi, lts, lsi,
                                            Zout, muout);
    k_lv<<<(SNT / 4) / 256, 256, 0, stream>>>(lvout, lts, lsi);
}